// Round 2
// baseline (220.699 us; speedup 1.0000x reference)
//
#include <hip/hip_runtime.h>
#include <hip/hip_bf16.h>

#define WIN 7
#define SHIFT_SZ 3
#define WSQ 49
#define CH 128
#define HW 56
#define LOG2E 1.4426950408889634f
#define QSCALE (0.17677669529663687f * LOG2E)

typedef short s16x8 __attribute__((ext_vector_type(8)));
typedef short s16x4 __attribute__((ext_vector_type(4)));
typedef float f32x4 __attribute__((ext_vector_type(4)));

// ---------------- prep kernels ----------------

__global__ void prep_weights(const float* __restrict__ qkv_kernel,
                             const float* __restrict__ proj_kernel,
                             __hip_bfloat16* __restrict__ ws) {
  int idx = blockIdx.x * 256 + threadIdx.x;
  if (idx < 49152) {                      // WqkvT [384][128]
    int n = idx >> 7, c = idx & 127;
    ws[idx] = __float2bfloat16(qkv_kernel[c * 384 + n]);
  }
  if (idx < 16384) {                      // WprojT [128][128]
    int n = idx >> 7, c = idx & 127;
    ws[49152 + idx] = __float2bfloat16(proj_kernel[c * 128 + n]);
  }
}

// tbl[win][h][t][s] = LOG2E * (rel_pos_bias(s,t) + shift_mask(s,t));
// rows t>=49 -> -43280 (kills padded keys), cols s>=49 (dead queries) -> 0
__global__ void prep_tbl(const float* __restrict__ rel_pos_table,
                         __hip_bfloat16* __restrict__ tbl) {
  int idx = blockIdx.x * 256 + threadIdx.x;   // 2^20 total
  int s = idx & 63;
  int t = (idx >> 6) & 63;
  int h = (idx >> 12) & 3;
  int win = idx >> 14;
  float v;
  if (t >= WSQ) v = -43280.f;
  else if (s >= WSQ) v = 0.f;
  else {
    int i1 = s / 7, j1 = s % 7, i2 = t / 7, j2 = t % 7;
    int ridx = (i1 - i2 + 6) * 13 + (j1 - j2 + 6);
    float bias = rel_pos_table[ridx * 4 + h];
    int wy = win >> 3, wx = win & 7;
    int rh1 = (wy < 7) ? 0 : (i1 < 4 ? 1 : 2);
    int rh2 = (wy < 7) ? 0 : (i2 < 4 ? 1 : 2);
    int rw1 = (wx < 7) ? 0 : (j1 < 4 ? 1 : 2);
    int rw2 = (wx < 7) ? 0 : (j2 < 4 ? 1 : 2);
    float mask = (rh1 == rh2 && rw1 == rw2) ? 0.f : -100.f;
    v = (bias + mask) * LOG2E;
  }
  tbl[idx] = __float2bfloat16(v);
}

// ---------------- fused main kernel ----------------
// one block = one window (4096 blocks), 512 threads = 8 waves
// LDS pool 54272 B (3 blocks/CU), fully time-multiplexed:
//   [0,17408)      x-stage [64][136]            (phase 1-2)
//   [0,18432)      q [4][64][36]                (phase 2b-3a)
//   [18432,36864)  k [4][64][36]                (phase 2b-3a)
//   [36864,53248)  vt [4][32][64] blk-swizzled  (phase 2b-3a)
//   [0,36864)      p [4][64][72]                (phase 3b, wave-local)
//   [36864,54272)  o [64][136]                  (phase 3b-4)

static __device__ __forceinline__ s16x8 ld2x64(const __hip_bfloat16* p) {
  s16x8 r;
  *(s16x4*)&r = *(const s16x4*)p;
  *(((s16x4*)&r) + 1) = *(const s16x4*)(p + 4);
  return r;
}

__launch_bounds__(512, 6)
__global__ void swin_attn(const float* __restrict__ x,
                          const float* __restrict__ qkv_bias,
                          const float* __restrict__ proj_bias,
                          const __hip_bfloat16* __restrict__ wqkvT,
                          const __hip_bfloat16* __restrict__ wprojT,
                          const __hip_bfloat16* __restrict__ tbl,
                          float* __restrict__ out) {
  __shared__ __align__(16) char smem[54272];
  __hip_bfloat16* a_lds  = (__hip_bfloat16*)smem;             // [64][136]
  __hip_bfloat16* q_lds  = (__hip_bfloat16*)smem;             // [4][64][36]
  __hip_bfloat16* k_lds  = (__hip_bfloat16*)(smem + 18432);   // [4][64][36]
  __hip_bfloat16* vt_lds = (__hip_bfloat16*)(smem + 36864);   // [4][32][64] swz
  __hip_bfloat16* p_lds  = (__hip_bfloat16*)smem;             // [4][64][72]
  __hip_bfloat16* o_lds  = (__hip_bfloat16*)(smem + 36864);   // [64][136]

  const int tid = threadIdx.x;
  const int lane = tid & 63;
  const int wv = tid >> 6;          // wave 0..7
  const int g = lane >> 4;          // quarter-wave group
  const int c = lane & 15;

  const int widx = blockIdx.x;
  const int b  = widx >> 6;
  const int wy = (widx >> 3) & 7;
  const int wx = widx & 7;
  const int win64 = widx & 63;

  // ---- phase 1: stage shifted x-window as bf16 (rows 49..63 zero) ----
  for (int it = tid; it < 1024; it += 512) {
    int s = it >> 4;
    int l16 = it & 15;
    union { s16x8 v; __hip_bfloat16 h[8]; } u;
    if (s < WSQ) {
      int i = s / 7, j = s - i * 7;
      int hh = wy * 7 + i + SHIFT_SZ; if (hh >= HW) hh -= HW;
      int ww = wx * 7 + j + SHIFT_SZ; if (ww >= HW) ww -= HW;
      const float4* src = (const float4*)(x + (((b * HW + hh) * HW + ww) * CH + l16 * 8));
      float4 f0 = src[0], f1 = src[1];
      u.h[0] = __float2bfloat16(f0.x); u.h[1] = __float2bfloat16(f0.y);
      u.h[2] = __float2bfloat16(f0.z); u.h[3] = __float2bfloat16(f0.w);
      u.h[4] = __float2bfloat16(f1.x); u.h[5] = __float2bfloat16(f1.y);
      u.h[6] = __float2bfloat16(f1.z); u.h[7] = __float2bfloat16(f1.w);
    } else {
      #pragma unroll
      for (int q = 0; q < 8; ++q) u.h[q] = __float2bfloat16(0.f);
    }
    *(s16x8*)(a_lds + s * 136 + l16 * 8) = u.v;
  }
  __syncthreads();

  // ---- phase 2a: QKV GEMM. wave wv: QK n-tiles {2wv,2wv+1} (n-major out),
  //      V n-tile {16+wv} (m-major out) ----
  f32x4 acc_qk[2][4];   // [ntl][mt]: rows n=16nt+4g+r, cols s=16mt+c
  f32x4 acc_v[4];       // [mt]:      rows s=16mt+4g+r, cols d=c
  #pragma unroll
  for (int ntl = 0; ntl < 2; ++ntl)
    #pragma unroll
    for (int mt = 0; mt < 4; ++mt) acc_qk[ntl][mt] = (f32x4){0.f, 0.f, 0.f, 0.f};
  #pragma unroll
  for (int mt = 0; mt < 4; ++mt) acc_v[mt] = (f32x4){0.f, 0.f, 0.f, 0.f};

  #pragma unroll
  for (int kt = 0; kt < 4; ++kt) {
    s16x8 af[4];
    #pragma unroll
    for (int mt = 0; mt < 4; ++mt)
      af[mt] = *(const s16x8*)(a_lds + (16 * mt + c) * 136 + kt * 32 + g * 8);
    #pragma unroll
    for (int ntl = 0; ntl < 2; ++ntl) {
      s16x8 bf = *(const s16x8*)(wqkvT + (16 * (2 * wv + ntl) + c) * 128 + kt * 32 + g * 8);
      #pragma unroll
      for (int mt = 0; mt < 4; ++mt)
        acc_qk[ntl][mt] = __builtin_amdgcn_mfma_f32_16x16x32_bf16(bf, af[mt], acc_qk[ntl][mt], 0, 0, 0);
    }
    s16x8 bv = *(const s16x8*)(wqkvT + (16 * (16 + wv) + c) * 128 + kt * 32 + g * 8);
    #pragma unroll
    for (int mt = 0; mt < 4; ++mt)
      acc_v[mt] = __builtin_amdgcn_mfma_f32_16x16x32_bf16(af[mt], bv, acc_v[mt], 0, 0, 0);
  }
  __syncthreads();   // all a_lds reads done; scatter may clobber it

  // ---- phase 2b: packed scatter ----
  {
    const float scale = (wv < 4) ? QSCALE : 1.0f;
    #pragma unroll
    for (int ntl = 0; ntl < 2; ++ntl) {
      int qt = 2 * wv + ntl;                       // 0..15
      int h = (qt >> 1) & 3;
      int d0 = (qt & 1) * 16 + 4 * g;
      float4 b4 = *(const float4*)(qkv_bias + qt * 16 + 4 * g);
      __hip_bfloat16* dst = (qt < 8 ? q_lds : k_lds) + h * 64 * 36 + d0;
      #pragma unroll
      for (int mt = 0; mt < 4; ++mt) {
        union { s16x4 v; __hip_bfloat16 h[4]; } u;
        u.h[0] = __float2bfloat16((acc_qk[ntl][mt][0] + b4.x) * scale);
        u.h[1] = __float2bfloat16((acc_qk[ntl][mt][1] + b4.y) * scale);
        u.h[2] = __float2bfloat16((acc_qk[ntl][mt][2] + b4.z) * scale);
        u.h[3] = __float2bfloat16((acc_qk[ntl][mt][3] + b4.w) * scale);
        *(s16x4*)(dst + (16 * mt + c) * 36) = u.v;
      }
    }
    // V: rows d=c+16(wv&1), cols s consecutive; swizzled 8-elem blocks
    int hv = wv >> 1;
    int d = (wv & 1) * 16 + c;
    float bv = qkv_bias[256 + wv * 16 + c];
    __hip_bfloat16* vdst = vt_lds + (hv * 32 + d) * 64;
    #pragma unroll
    for (int mt = 0; mt < 4; ++mt) {
      int s0 = 16 * mt + 4 * g;
      union { s16x4 v; __hip_bfloat16 h[4]; } u;
      #pragma unroll
      for (int r = 0; r < 4; ++r) u.h[r] = __float2bfloat16(acc_v[mt][r] + bv);
      *(s16x4*)(vdst + (((s0 >> 3) ^ (c & 7)) << 3) + (s0 & 7)) = u.v;
    }
  }
  __syncthreads();   // scatter visible

  // ---- phase 3a: preload all fragments to registers ----
  const int h3 = wv >> 1;
  const int mh = wv & 1;
  s16x8 qf[2], kf[4], vf[2][2];
  #pragma unroll
  for (int m = 0; m < 2; ++m)
    qf[m] = ld2x64(q_lds + (h3 * 64 + 16 * (2 * mh + m) + c) * 36 + g * 8);
  #pragma unroll
  for (int nt = 0; nt < 4; ++nt)
    kf[nt] = ld2x64(k_lds + (h3 * 64 + 16 * nt + c) * 36 + g * 8);
  #pragma unroll
  for (int kt = 0; kt < 2; ++kt)
    #pragma unroll
    for (int ntd = 0; ntd < 2; ++ntd) {
      int row = h3 * 32 + 16 * ntd + c;
      int blk = (4 * kt + g) ^ (c & 7);
      vf[kt][ntd] = *(const s16x8*)(vt_lds + row * 64 + blk * 8);
    }
  __syncthreads();   // all q/k/vt reads done; p/o writes may proceed

  // ---- phase 3b: QK^T (t-major), softmax in-register, packed P write ----
  #pragma unroll
  for (int m = 0; m < 2; ++m) {
    f32x4 sc[4];
    #pragma unroll
    for (int nt = 0; nt < 4; ++nt) {
      sc[nt] = (f32x4){0.f, 0.f, 0.f, 0.f};
      sc[nt] = __builtin_amdgcn_mfma_f32_16x16x32_bf16(kf[nt], qf[m], sc[nt], 0, 0, 0);
    }
    const __hip_bfloat16* tb = tbl + (((win64 << 2) + h3) << 12) + 16 * (2 * mh + m) + c;
    #pragma unroll
    for (int nt = 0; nt < 4; ++nt)
      #pragma unroll
      for (int r = 0; r < 4; ++r)
        sc[nt][r] += __bfloat162float(tb[(16 * nt + 4 * g + r) << 6]);
    float mx = -1e30f;
    #pragma unroll
    for (int nt = 0; nt < 4; ++nt)
      #pragma unroll
      for (int r = 0; r < 4; ++r) mx = fmaxf(mx, sc[nt][r]);
    mx = fmaxf(mx, __shfl_xor(mx, 16));
    mx = fmaxf(mx, __shfl_xor(mx, 32));
    float sum = 0.f;
    #pragma unroll
    for (int nt = 0; nt < 4; ++nt)
      #pragma unroll
      for (int r = 0; r < 4; ++r) {
        float e = __builtin_amdgcn_exp2f(sc[nt][r] - mx);
        sc[nt][r] = e;
        sum += e;
      }
    sum += __shfl_xor(sum, 16);
    sum += __shfl_xor(sum, 32);
    float inv = __builtin_amdgcn_rcpf(sum);
    __hip_bfloat16* prow = p_lds + (h3 * 64 + 16 * (2 * mh + m) + c) * 72;
    #pragma unroll
    for (int nt = 0; nt < 4; ++nt) {
      union { s16x4 v; __hip_bfloat16 h[4]; } u;
      #pragma unroll
      for (int r = 0; r < 4; ++r) u.h[r] = __float2bfloat16(sc[nt][r] * inv);
      *(s16x4*)(prow + 16 * nt + 4 * g) = u.v;
    }
  }

  // ---- PV: O = P @ V (wave-local p round trip, no barrier) ----
  f32x4 oacc[2][2];
  #pragma unroll
  for (int m = 0; m < 2; ++m)
    #pragma unroll
    for (int ntd = 0; ntd < 2; ++ntd) oacc[m][ntd] = (f32x4){0.f, 0.f, 0.f, 0.f};
  #pragma unroll
  for (int kt = 0; kt < 2; ++kt) {
    #pragma unroll
    for (int m = 0; m < 2; ++m) {
      s16x8 pf = *(const s16x8*)(p_lds + (h3 * 64 + 16 * (2 * mh + m) + c) * 72 + kt * 32 + g * 8);
      #pragma unroll
      for (int ntd = 0; ntd < 2; ++ntd)
        oacc[m][ntd] = __builtin_amdgcn_mfma_f32_16x16x32_bf16(pf, vf[kt][ntd], oacc[m][ntd], 0, 0, 0);
    }
  }
  #pragma unroll
  for (int m = 0; m < 2; ++m)
    #pragma unroll
    for (int ntd = 0; ntd < 2; ++ntd)
      #pragma unroll
      for (int r = 0; r < 4; ++r)
        o_lds[(16 * (2 * mh + m) + 4 * g + r) * 136 + h3 * 32 + 16 * ntd + c] =
            __float2bfloat16(oacc[m][ntd][r]);
  __syncthreads();

  // ---- phase 4: proj GEMM (n-major out -> float4 stores). wave owns n-tile wv
  {
    f32x4 pacc[4];
    #pragma unroll
    for (int mt = 0; mt < 4; ++mt) pacc[mt] = (f32x4){0.f, 0.f, 0.f, 0.f};
    #pragma unroll
    for (int kt = 0; kt < 4; ++kt) {
      s16x8 bfp = *(const s16x8*)(wprojT + (16 * wv + c) * 128 + kt * 32 + g * 8);
      #pragma unroll
      for (int mt = 0; mt < 4; ++mt) {
        s16x8 afo = *(const s16x8*)(o_lds + (16 * mt + c) * 136 + kt * 32 + g * 8);
        pacc[mt] = __builtin_amdgcn_mfma_f32_16x16x32_bf16(bfp, afo, pacc[mt], 0, 0, 0);
      }
    }
    float4 pb4 = *(const float4*)(proj_bias + 16 * wv + 4 * g);
    #pragma unroll
    for (int mt = 0; mt < 4; ++mt) {
      int s = 16 * mt + c;
      if (s < WSQ) {
        int i = s / 7, j = s - i * 7;
        int hh = wy * 7 + i + SHIFT_SZ; if (hh >= HW) hh -= HW;
        int ww = wx * 7 + j + SHIFT_SZ; if (ww >= HW) ww -= HW;
        float4 v;
        v.x = pacc[mt][0] + pb4.x;
        v.y = pacc[mt][1] + pb4.y;
        v.z = pacc[mt][2] + pb4.z;
        v.w = pacc[mt][3] + pb4.w;
        *(float4*)(out + ((b * HW + hh) * HW + ww) * CH + 16 * wv + 4 * g) = v;
      }
    }
  }
}

extern "C" void kernel_launch(void* const* d_in, const int* in_sizes, int n_in,
                              void* d_out, int out_size, void* d_ws, size_t ws_size,
                              hipStream_t stream) {
  const float* x            = (const float*)d_in[0];
  const float* qkv_kernel   = (const float*)d_in[1];
  const float* qkv_bias     = (const float*)d_in[2];
  const float* proj_kernel  = (const float*)d_in[3];
  const float* proj_bias    = (const float*)d_in[4];
  const float* rel_pos_tbl  = (const float*)d_in[5];
  float* out = (float*)d_out;

  __hip_bfloat16* wsb    = (__hip_bfloat16*)d_ws;
  __hip_bfloat16* wqkvT  = wsb;            // 49152 elems
  __hip_bfloat16* wprojT = wsb + 49152;    // 16384 elems
  __hip_bfloat16* tbl    = wsb + 65536;    // 1048576 elems

  prep_weights<<<dim3(192), dim3(256), 0, stream>>>(qkv_kernel, proj_kernel, wsb);
  prep_tbl<<<dim3(4096), dim3(256), 0, stream>>>(rel_pos_tbl, tbl);
  swin_attn<<<dim3(4096), dim3(512), 0, stream>>>(x, qkv_bias, proj_bias,
                                                  wqkvT, wprojT, tbl, out);
}

// Round 3
// 129.753 us; speedup vs baseline: 1.7009x; 1.7009x over previous
//
#include <hip/hip_runtime.h>
#include <hip/hip_bf16.h>

#define WIN 7
#define SHIFT_SZ 3
#define WSQ 49
#define CH 128
#define HW 56
#define LOG2E 1.4426950408889634f
#define QSCALE (0.17677669529663687f * LOG2E)

typedef short s16x8 __attribute__((ext_vector_type(8)));
typedef short s16x4 __attribute__((ext_vector_type(4)));
typedef float f32x4 __attribute__((ext_vector_type(4)));

// ---------------- prep kernels ----------------

__global__ void prep_weights(const float* __restrict__ qkv_kernel,
                             const float* __restrict__ proj_kernel,
                             __hip_bfloat16* __restrict__ ws) {
  int idx = blockIdx.x * 256 + threadIdx.x;
  if (idx < 49152) {                      // WqkvT [384][128]
    int n = idx >> 7, c = idx & 127;
    ws[idx] = __float2bfloat16(qkv_kernel[c * 384 + n]);
  }
  if (idx < 16384) {                      // WprojT [128][128]
    int n = idx >> 7, c = idx & 127;
    ws[49152 + idx] = __float2bfloat16(proj_kernel[c * 128 + n]);
  }
}

// tbl[win][h][s][t] = LOG2E * (rel_pos_bias(s,t) + shift_mask(s,t));
// cols t>=49 -> -43280 (kills padded keys), rows s>=49 (dead queries) -> 0
__global__ void prep_tbl(const float* __restrict__ rel_pos_table,
                         __hip_bfloat16* __restrict__ tbl) {
  int idx = blockIdx.x * 256 + threadIdx.x;   // 2^20 total
  int t = idx & 63;
  int s = (idx >> 6) & 63;
  int h = (idx >> 12) & 3;
  int win = idx >> 14;
  float v;
  if (t >= WSQ) v = -43280.f;
  else if (s >= WSQ) v = 0.f;
  else {
    int i1 = s / 7, j1 = s % 7, i2 = t / 7, j2 = t % 7;
    int ridx = (i1 - i2 + 6) * 13 + (j1 - j2 + 6);
    float bias = rel_pos_table[ridx * 4 + h];
    int wy = win >> 3, wx = win & 7;
    int rh1 = (wy < 7) ? 0 : (i1 < 4 ? 1 : 2);
    int rh2 = (wy < 7) ? 0 : (i2 < 4 ? 1 : 2);
    int rw1 = (wx < 7) ? 0 : (j1 < 4 ? 1 : 2);
    int rw2 = (wx < 7) ? 0 : (j2 < 4 ? 1 : 2);
    float mask = (rh1 == rh2 && rw1 == rw2) ? 0.f : -100.f;
    v = (bias + mask) * LOG2E;
  }
  tbl[idx] = __float2bfloat16(v);
}

// ---------------- fused main kernel ----------------
// one block = one window (4096 blocks), 512 threads = 8 waves
// LDS pool 53248 B (3 blocks/CU), time-multiplexed:
//   [0,17408)      x-stage [64][136]            (phase 1-2)
//   [0,18432)      q [4][64][36]                (post-b2 .. b4)
//   [18432,36864)  k [4][64][36]                (pre-b2 .. b4)
//   [36864,53248)  vt [4][32][64] blk-swizzled  (pass A .. PV)
//   [0,36864)      p [4][64][72]                (post-b4, wave-local)
//   [0,17408)      o [64][136]                  (post-b5 .. proj)

static __device__ __forceinline__ s16x8 ld2x64(const __hip_bfloat16* p) {
  s16x8 r;
  *(s16x4*)&r = *(const s16x4*)p;
  *(((s16x4*)&r) + 1) = *(const s16x4*)(p + 4);
  return r;
}

__launch_bounds__(512, 6)
__global__ void swin_attn(const float* __restrict__ x,
                          const float* __restrict__ qkv_bias,
                          const float* __restrict__ proj_bias,
                          const __hip_bfloat16* __restrict__ wqkvT,
                          const __hip_bfloat16* __restrict__ wprojT,
                          const __hip_bfloat16* __restrict__ tbl,
                          float* __restrict__ out) {
  __shared__ __align__(16) char smem[53248];
  __hip_bfloat16* a_lds  = (__hip_bfloat16*)smem;             // [64][136]
  __hip_bfloat16* q_lds  = (__hip_bfloat16*)smem;             // [4][64][36]
  __hip_bfloat16* k_lds  = (__hip_bfloat16*)(smem + 18432);   // [4][64][36]
  __hip_bfloat16* vt_lds = (__hip_bfloat16*)(smem + 36864);   // [4][32][64] swz
  __hip_bfloat16* p_lds  = (__hip_bfloat16*)smem;             // [4][64][72]
  __hip_bfloat16* o_lds  = (__hip_bfloat16*)smem;             // [64][136]

  const int tid = threadIdx.x;
  const int lane = tid & 63;
  const int wv = tid >> 6;          // wave 0..7
  const int g = lane >> 4;          // quarter-wave group
  const int c = lane & 15;

  const int widx = blockIdx.x;
  const int b  = widx >> 6;
  const int wy = (widx >> 3) & 7;
  const int wx = widx & 7;
  const int win64 = widx & 63;

  // ---- phase 1: stage shifted x-window as bf16 (rows 49..63 zero) ----
  for (int it = tid; it < 1024; it += 512) {
    int s = it >> 4;
    int l16 = it & 15;
    union { s16x8 v; __hip_bfloat16 h[8]; } u;
    if (s < WSQ) {
      int i = s / 7, j = s - i * 7;
      int hh = wy * 7 + i + SHIFT_SZ; if (hh >= HW) hh -= HW;
      int ww = wx * 7 + j + SHIFT_SZ; if (ww >= HW) ww -= HW;
      const float4* src = (const float4*)(x + (((b * HW + hh) * HW + ww) * CH + l16 * 8));
      float4 f0 = src[0], f1 = src[1];
      u.h[0] = __float2bfloat16(f0.x); u.h[1] = __float2bfloat16(f0.y);
      u.h[2] = __float2bfloat16(f0.z); u.h[3] = __float2bfloat16(f0.w);
      u.h[4] = __float2bfloat16(f1.x); u.h[5] = __float2bfloat16(f1.y);
      u.h[6] = __float2bfloat16(f1.z); u.h[7] = __float2bfloat16(f1.w);
    } else {
      #pragma unroll
      for (int q = 0; q < 8; ++q) u.h[q] = __float2bfloat16(0.f);
    }
    *(s16x8*)(a_lds + s * 136 + l16 * 8) = u.v;
  }
  __syncthreads();   // b1

  // ---- phase 2, pass A: V tile (n-tile 16+wv), m-major out ----
  {
    f32x4 acc_v[4];
    #pragma unroll
    for (int mt = 0; mt < 4; ++mt) acc_v[mt] = (f32x4){0.f, 0.f, 0.f, 0.f};
    #pragma unroll
    for (int kt = 0; kt < 4; ++kt) {
      s16x8 bv = *(const s16x8*)(wqkvT + (16 * (16 + wv) + c) * 128 + kt * 32 + g * 8);
      #pragma unroll
      for (int mt = 0; mt < 4; ++mt) {
        s16x8 af = *(const s16x8*)(a_lds + (16 * mt + c) * 136 + kt * 32 + g * 8);
        acc_v[mt] = __builtin_amdgcn_mfma_f32_16x16x32_bf16(af, bv, acc_v[mt], 0, 0, 0);
      }
    }
    // scatter V^T: rows d, cols t; 4-elem packed, 8-elem-block swizzle
    int hv = wv >> 1;
    int d = (wv & 1) * 16 + c;
    float bvb = qkv_bias[256 + wv * 16 + c];
    __hip_bfloat16* vdst = vt_lds + (hv * 32 + d) * 64;
    #pragma unroll
    for (int mt = 0; mt < 4; ++mt) {
      int s0 = 16 * mt + 4 * g;
      union { s16x4 v; __hip_bfloat16 h[4]; } u;
      #pragma unroll
      for (int r = 0; r < 4; ++r) u.h[r] = __float2bfloat16(acc_v[mt][r] + bvb);
      *(s16x4*)(vdst + (((s0 >> 3) ^ (c & 7)) << 3) + (s0 & 7)) = u.v;
    }
  }

  // ---- phase 2, pass B: Q/K tiles {2wv, 2wv+1}, n-major out ----
  {
    f32x4 acc[2][4];
    #pragma unroll
    for (int ntl = 0; ntl < 2; ++ntl)
      #pragma unroll
      for (int mt = 0; mt < 4; ++mt) acc[ntl][mt] = (f32x4){0.f, 0.f, 0.f, 0.f};
    #pragma unroll
    for (int kt = 0; kt < 4; ++kt) {
      s16x8 af[4];
      #pragma unroll
      for (int mt = 0; mt < 4; ++mt)
        af[mt] = *(const s16x8*)(a_lds + (16 * mt + c) * 136 + kt * 32 + g * 8);
      #pragma unroll
      for (int ntl = 0; ntl < 2; ++ntl) {
        s16x8 bf = *(const s16x8*)(wqkvT + (16 * (2 * wv + ntl) + c) * 128 + kt * 32 + g * 8);
        #pragma unroll
        for (int mt = 0; mt < 4; ++mt)
          acc[ntl][mt] = __builtin_amdgcn_mfma_f32_16x16x32_bf16(bf, af[mt], acc[ntl][mt], 0, 0, 0);
      }
    }
    const float scale = (wv < 4) ? QSCALE : 1.0f;
    // waves 4-7 own K tiles -> region disjoint from a_lds, scatter pre-barrier
    if (wv >= 4) {
      #pragma unroll
      for (int ntl = 0; ntl < 2; ++ntl) {
        int qt = 2 * wv + ntl;
        int h = (qt >> 1) & 3;
        int d0 = (qt & 1) * 16 + 4 * g;
        float4 b4 = *(const float4*)(qkv_bias + qt * 16 + 4 * g);
        __hip_bfloat16* dst = k_lds + h * 2304 + d0;
        #pragma unroll
        for (int mt = 0; mt < 4; ++mt) {
          union { s16x4 v; __hip_bfloat16 h[4]; } u;
          u.h[0] = __float2bfloat16((acc[ntl][mt][0] + b4.x) * scale);
          u.h[1] = __float2bfloat16((acc[ntl][mt][1] + b4.y) * scale);
          u.h[2] = __float2bfloat16((acc[ntl][mt][2] + b4.z) * scale);
          u.h[3] = __float2bfloat16((acc[ntl][mt][3] + b4.w) * scale);
          *(s16x4*)(dst + (16 * mt + c) * 36) = u.v;
        }
      }
    }
    __syncthreads();   // b2: all a_lds reads done
    if (wv < 4) {
      #pragma unroll
      for (int ntl = 0; ntl < 2; ++ntl) {
        int qt = 2 * wv + ntl;
        int h = (qt >> 1) & 3;
        int d0 = (qt & 1) * 16 + 4 * g;
        float4 b4 = *(const float4*)(qkv_bias + qt * 16 + 4 * g);
        __hip_bfloat16* dst = q_lds + h * 2304 + d0;
        #pragma unroll
        for (int mt = 0; mt < 4; ++mt) {
          union { s16x4 v; __hip_bfloat16 h[4]; } u;
          u.h[0] = __float2bfloat16((acc[ntl][mt][0] + b4.x) * scale);
          u.h[1] = __float2bfloat16((acc[ntl][mt][1] + b4.y) * scale);
          u.h[2] = __float2bfloat16((acc[ntl][mt][2] + b4.z) * scale);
          u.h[3] = __float2bfloat16((acc[ntl][mt][3] + b4.w) * scale);
          *(s16x4*)(dst + (16 * mt + c) * 36) = u.v;
        }
      }
    }
  }
  __syncthreads();   // b3: q/k/vt visible

  // ---- phase 3a: preload q/k fragments ----
  const int h3 = wv >> 1;
  const int mh = wv & 1;
  s16x8 qf[2], kf[4];
  #pragma unroll
  for (int m = 0; m < 2; ++m)
    qf[m] = ld2x64(q_lds + (h3 * 64 + 16 * (2 * mh + m) + c) * 36 + g * 8);
  #pragma unroll
  for (int nt = 0; nt < 4; ++nt)
    kf[nt] = ld2x64(k_lds + (h3 * 64 + 16 * nt + c) * 36 + g * 8);
  __syncthreads();   // b4: q/k reads done; p writes may clobber

  // ---- phase 3b: QK^T (t-major), in-register softmax, packed P write ----
  #pragma unroll
  for (int m = 0; m < 2; ++m) {
    f32x4 sc[4];
    #pragma unroll
    for (int nt = 0; nt < 4; ++nt) {
      sc[nt] = (f32x4){0.f, 0.f, 0.f, 0.f};
      sc[nt] = __builtin_amdgcn_mfma_f32_16x16x32_bf16(kf[nt], qf[m], sc[nt], 0, 0, 0);
    }
    const __hip_bfloat16* tb =
        tbl + (((win64 << 2) + h3) << 12) + (16 * (2 * mh + m) + c) * 64;
    #pragma unroll
    for (int nt = 0; nt < 4; ++nt) {
      union { s16x4 v; __hip_bfloat16 h[4]; } tv;
      tv.v = *(const s16x4*)(tb + 16 * nt + 4 * g);
      #pragma unroll
      for (int r = 0; r < 4; ++r) sc[nt][r] += __bfloat162float(tv.h[r]);
    }
    float mx = -1e30f;
    #pragma unroll
    for (int nt = 0; nt < 4; ++nt)
      #pragma unroll
      for (int r = 0; r < 4; ++r) mx = fmaxf(mx, sc[nt][r]);
    mx = fmaxf(mx, __shfl_xor(mx, 16));
    mx = fmaxf(mx, __shfl_xor(mx, 32));
    float sum = 0.f;
    #pragma unroll
    for (int nt = 0; nt < 4; ++nt)
      #pragma unroll
      for (int r = 0; r < 4; ++r) {
        float e = __builtin_amdgcn_exp2f(sc[nt][r] - mx);
        sc[nt][r] = e;
        sum += e;
      }
    sum += __shfl_xor(sum, 16);
    sum += __shfl_xor(sum, 32);
    float inv = __builtin_amdgcn_rcpf(sum);
    __hip_bfloat16* prow = p_lds + (h3 * 64 + 16 * (2 * mh + m) + c) * 72;
    #pragma unroll
    for (int nt = 0; nt < 4; ++nt) {
      union { s16x4 v; __hip_bfloat16 h[4]; } u;
      #pragma unroll
      for (int r = 0; r < 4; ++r) u.h[r] = __float2bfloat16(sc[nt][r] * inv);
      *(s16x4*)(prow + 16 * nt + 4 * g) = u.v;
    }
  }

  // ---- PV: O = P @ V, swapped operands -> d-major out ----
  f32x4 oacc[2][2];
  #pragma unroll
  for (int m = 0; m < 2; ++m)
    #pragma unroll
    for (int ntd = 0; ntd < 2; ++ntd) oacc[m][ntd] = (f32x4){0.f, 0.f, 0.f, 0.f};
  #pragma unroll
  for (int kt = 0; kt < 2; ++kt) {
    s16x8 vfr[2], pfr[2];
    #pragma unroll
    for (int ntd = 0; ntd < 2; ++ntd)
      vfr[ntd] = *(const s16x8*)(vt_lds + (h3 * 32 + 16 * ntd + c) * 64 +
                                 (((4 * kt + g) ^ (c & 7)) << 3));
    #pragma unroll
    for (int m = 0; m < 2; ++m)
      pfr[m] = *(const s16x8*)(p_lds + (h3 * 64 + 16 * (2 * mh + m) + c) * 72 +
                               kt * 32 + g * 8);
    #pragma unroll
    for (int m = 0; m < 2; ++m)
      #pragma unroll
      for (int ntd = 0; ntd < 2; ++ntd)
        oacc[m][ntd] = __builtin_amdgcn_mfma_f32_16x16x32_bf16(vfr[ntd], pfr[m], oacc[m][ntd], 0, 0, 0);
  }
  __syncthreads();   // b5: p/vt reads done; o writes may clobber

  #pragma unroll
  for (int m = 0; m < 2; ++m)
    #pragma unroll
    for (int ntd = 0; ntd < 2; ++ntd) {
      union { s16x4 v; __hip_bfloat16 h[4]; } u;
      #pragma unroll
      for (int r = 0; r < 4; ++r) u.h[r] = __float2bfloat16(oacc[m][ntd][r]);
      *(s16x4*)(o_lds + (16 * (2 * mh + m) + c) * 136 + h3 * 32 + 16 * ntd + 4 * g) = u.v;
    }
  __syncthreads();   // b6: o visible

  // ---- phase 4: proj GEMM (n-major out -> float4 stores) ----
  {
    f32x4 pacc[4];
    #pragma unroll
    for (int mt = 0; mt < 4; ++mt) pacc[mt] = (f32x4){0.f, 0.f, 0.f, 0.f};
    #pragma unroll
    for (int kt = 0; kt < 4; ++kt) {
      s16x8 bfp = *(const s16x8*)(wprojT + (16 * wv + c) * 128 + kt * 32 + g * 8);
      #pragma unroll
      for (int mt = 0; mt < 4; ++mt) {
        s16x8 afo = *(const s16x8*)(o_lds + (16 * mt + c) * 136 + kt * 32 + g * 8);
        pacc[mt] = __builtin_amdgcn_mfma_f32_16x16x32_bf16(bfp, afo, pacc[mt], 0, 0, 0);
      }
    }
    float4 pb4 = *(const float4*)(proj_bias + 16 * wv + 4 * g);
    #pragma unroll
    for (int mt = 0; mt < 4; ++mt) {
      int s = 16 * mt + c;
      if (s < WSQ) {
        int i = s / 7, j = s - i * 7;
        int hh = wy * 7 + i + SHIFT_SZ; if (hh >= HW) hh -= HW;
        int ww = wx * 7 + j + SHIFT_SZ; if (ww >= HW) ww -= HW;
        float4 v;
        v.x = pacc[mt][0] + pb4.x;
        v.y = pacc[mt][1] + pb4.y;
        v.z = pacc[mt][2] + pb4.z;
        v.w = pacc[mt][3] + pb4.w;
        *(float4*)(out + ((b * HW + hh) * HW + ww) * CH + 16 * wv + 4 * g) = v;
      }
    }
  }
}

extern "C" void kernel_launch(void* const* d_in, const int* in_sizes, int n_in,
                              void* d_out, int out_size, void* d_ws, size_t ws_size,
                              hipStream_t stream) {
  const float* x            = (const float*)d_in[0];
  const float* qkv_kernel   = (const float*)d_in[1];
  const float* qkv_bias     = (const float*)d_in[2];
  const float* proj_kernel  = (const float*)d_in[3];
  const float* proj_bias    = (const float*)d_in[4];
  const float* rel_pos_tbl  = (const float*)d_in[5];
  float* out = (float*)d_out;

  __hip_bfloat16* wsb    = (__hip_bfloat16*)d_ws;
  __hip_bfloat16* wqkvT  = wsb;            // 49152 elems
  __hip_bfloat16* wprojT = wsb + 49152;    // 16384 elems
  __hip_bfloat16* tbl    = wsb + 65536;    // 1048576 elems

  prep_weights<<<dim3(192), dim3(256), 0, stream>>>(qkv_kernel, proj_kernel, wsb);
  prep_tbl<<<dim3(4096), dim3(256), 0, stream>>>(rel_pos_tbl, tbl);
  swin_attn<<<dim3(4096), dim3(512), 0, stream>>>(x, qkv_bias, proj_bias,
                                                  wqkvT, wprojT, tbl, out);
}